// Round 2
// baseline (959.669 us; speedup 1.0000x reference)
//
#include <hip/hip_runtime.h>
#include <hip/hip_bf16.h>
#include <cmath>

// ---------------------------------------------------------------------------
// GCN: out = tanh(relu(relu(relu(relu(P(P(P(P(xW1+..)..) .. ))Wf1+bf1)Wf2+bf2
// P = D^-1/2 (A+I) D^-1/2 applied via CSR (dst-sorted) gather-sum, no atomics.
// Associativity: aggregate at the *narrower* width of each layer.
// NOTE: harness delivers integer inputs as int32 (edge_index is int32 here,
// NOT int64 as in the jax reference) — round-1 crash was int64 misread.
// ---------------------------------------------------------------------------

__global__ void zero_kernel(int* p, int n) {
    int i = blockIdx.x * 256 + threadIdx.x;
    if (i < n) p[i] = 0;
}

__global__ void deg_kernel(const int* __restrict__ dst, int* __restrict__ cnt, int E) {
    int e = blockIdx.x * 256 + threadIdx.x;
    if (e < E) atomicAdd(&cnt[dst[e]], 1);
}

__global__ void dinv_kernel(const int* __restrict__ cnt, float* __restrict__ dinv, int N) {
    int i = blockIdx.x * 256 + threadIdx.x;
    if (i < N) dinv[i] = rsqrtf((float)cnt[i] + 1.0f);
}

// --- 3-kernel exclusive scan over per-node counts (N <= 512*256) -----------
__global__ void scan1_kernel(const int* __restrict__ cnt, int* __restrict__ row_ptr,
                             int* __restrict__ blk, int N) {
    __shared__ int s[256];
    int t = threadIdx.x;
    int idx = blockIdx.x * 256 + t;
    int v = (idx < N) ? cnt[idx] : 0;
    s[t] = v; __syncthreads();
    for (int off = 1; off < 256; off <<= 1) {
        int x = (t >= off) ? s[t - off] : 0;
        __syncthreads();
        s[t] += x;
        __syncthreads();
    }
    if (idx < N) row_ptr[idx] = s[t] - v;       // block-local exclusive
    if (t == 255) blk[blockIdx.x] = s[255];     // block total
}

__global__ void scan2_kernel(int* __restrict__ blk, int NB) {
    __shared__ int s[512];
    int t = threadIdx.x;
    int v = (t < NB) ? blk[t] : 0;
    s[t] = v; __syncthreads();
    for (int off = 1; off < 512; off <<= 1) {
        int x = (t >= off) ? s[t - off] : 0;
        __syncthreads();
        s[t] += x;
        __syncthreads();
    }
    if (t < NB) blk[t] = s[t] - v;              // exclusive over block totals
}

__global__ void scan3_kernel(int* __restrict__ row_ptr, const int* __restrict__ blk,
                             int* __restrict__ cursor, int N, int E) {
    int idx = blockIdx.x * 256 + threadIdx.x;
    if (idx < N) {
        int v = row_ptr[idx] + blk[blockIdx.x];
        row_ptr[idx] = v;
        cursor[idx] = v;
    }
    if (idx == 0) row_ptr[N] = E;
}

__global__ void fill_kernel(const int* __restrict__ src, const int* __restrict__ dst,
                            const float* __restrict__ dinv, int* __restrict__ cursor,
                            int* __restrict__ csr_src, float* __restrict__ csr_w, int E) {
    int e = blockIdx.x * 256 + threadIdx.x;
    if (e >= E) return;
    int s = src[e];
    int d = dst[e];
    float w = dinv[s] * dinv[d];
    int pos = atomicAdd(&cursor[d], 1);
    csr_src[pos] = s;
    csr_w[pos] = w;
}

// --- aggregation: out[i,:] = sum_e w_e * z[src_e,:] + dinv[i]^2 * z[i,:] ----
// one wave per node; 64/F edge-slots per wave; lanes within a slot read a
// contiguous F-float row of z (coalesced). Butterfly shuffle over slot bits.
template<int F, bool L1MODE>
__global__ void agg_kernel(const float* __restrict__ z, const int* __restrict__ row_ptr,
                           const int* __restrict__ csr_src, const float* __restrict__ csr_w,
                           const float* __restrict__ dinv, const float* __restrict__ bias,
                           float* __restrict__ out, int N) {
    constexpr int S = 64 / F;
    const int t = threadIdx.x;
    const int wave = t >> 6;
    const int lane = t & 63;
    const int slot = lane / F;
    const int f = lane % F;
    const int i = blockIdx.x * 4 + wave;
    if (i >= N) return;                        // wave-uniform exit
    const int start = row_ptr[i];
    const int end = row_ptr[i + 1];
    float acc = 0.f;
    for (int e = start + slot; e < end; e += S) {
        int s = csr_src[e];
        float w = csr_w[e];
        acc += w * z[(size_t)s * F + f];
    }
#pragma unroll
    for (int off = F; off < 64; off <<= 1) acc += __shfl_xor(acc, off);
    if (slot == 0) {
        float di = dinv[i];
        float r = acc + di * di * z[(size_t)i * F + f];
        if (L1MODE) r = fmaxf(r + bias[f], 0.f);
        out[(size_t)i * F + f] = r;
    }
}

// --- GEMM: out[i,m] = act(sum_k A[i,k] * W[k,m] (+ b[m])) -------------------
// W^T staged in LDS with +4 padding (odd granule stride -> no bank conflicts);
// A row read via float4 (broadcast across the M threads sharing a row).
template<int K, int M, bool BIAS_RELU>
__global__ void gemm_kernel(const float* __restrict__ A, const float* __restrict__ W,
                            const float* __restrict__ bias, float* __restrict__ out, int N) {
    constexpr int KP = K + 4;
    __shared__ float wt[M * KP];
    __shared__ float bs[M];
    const int t = threadIdx.x;
    for (int idx = t; idx < K * M; idx += 256) {
        int k = idx / M, m2 = idx % M;
        wt[m2 * KP + k] = W[idx];
    }
    if (BIAS_RELU) { if (t < M) bs[t] = bias[t]; }
    __syncthreads();
    constexpr int R = 256 / M;                 // rows per block
    const int m = t % M;
    const int rs = t / M;
    const int row = blockIdx.x * R + rs;
    if (row >= N) return;
    const float* a = A + (size_t)row * K;
    const float* w = &wt[m * KP];
    float acc = 0.f;
#pragma unroll
    for (int k = 0; k < K; k += 4) {
        float4 av = *(const float4*)(a + k);
        float4 wv = *(const float4*)(w + k);
        acc += av.x * wv.x + av.y * wv.y + av.z * wv.z + av.w * wv.w;
    }
    if (BIAS_RELU) acc = fmaxf(acc + bs[m], 0.f);
    out[(size_t)row * M + m] = acc;
}

// --- final FC: K=32, M=10, tanh --------------------------------------------
__global__ void fc2_tanh_kernel(const float* __restrict__ A, const float* __restrict__ W,
                                const float* __restrict__ bias, float* __restrict__ out, int N) {
    __shared__ float wt[10][36];
    __shared__ float bs[10];
    int t = threadIdx.x;
    for (int idx = t; idx < 320; idx += 256) { int k = idx / 10, m = idx % 10; wt[m][k] = W[idx]; }
    if (t < 10) bs[t] = bias[t];
    __syncthreads();
    int row = blockIdx.x * 256 + t;
    if (row >= N) return;
    float a[32];
    const float4* ap = (const float4*)(A + (size_t)row * 32);
#pragma unroll
    for (int j = 0; j < 8; j++) {
        float4 v = ap[j];
        a[4 * j] = v.x; a[4 * j + 1] = v.y; a[4 * j + 2] = v.z; a[4 * j + 3] = v.w;
    }
#pragma unroll
    for (int m = 0; m < 10; m++) {
        float acc = bs[m];
#pragma unroll
        for (int k = 0; k < 32; k++) acc += a[k] * wt[m][k];
        out[(size_t)row * 10 + m] = tanhf(acc);
    }
}

extern "C" void kernel_launch(void* const* d_in, const int* in_sizes, int n_in,
                              void* d_out, int out_size, void* d_ws, size_t ws_size,
                              hipStream_t stream) {
    const float* x   = (const float*)d_in[0];
    const int*   ei  = (const int*)d_in[1];     // int32 on device (harness contract)
    const float* W1  = (const float*)d_in[2];
    const float* b1  = (const float*)d_in[3];
    const float* W2  = (const float*)d_in[4];
    const float* b2  = (const float*)d_in[5];
    const float* W3  = (const float*)d_in[6];
    const float* b3  = (const float*)d_in[7];
    const float* W4  = (const float*)d_in[8];
    const float* b4  = (const float*)d_in[9];
    const float* Wf1 = (const float*)d_in[10];
    const float* bf1 = (const float*)d_in[11];
    const float* Wf2 = (const float*)d_in[12];
    const float* bf2 = (const float*)d_in[13];

    const int N = in_sizes[0] / 128;   // 100000
    const int E = in_sizes[1] / 2;     // 1600000
    const int* e_src = ei;
    const int* e_dst = ei + E;

    // workspace carve (256B aligned); total ~91 MB
    char* p = (char*)d_ws;
    auto carve = [&](size_t bytes) -> void* {
        void* r = (void*)p;
        p += (bytes + 255) & ~(size_t)255;
        return r;
    };
    int*   cnt     = (int*)carve((size_t)N * 4);          // also reused as cursor
    float* dinv    = (float*)carve((size_t)N * 4);
    int*   row_ptr = (int*)carve((size_t)(N + 1) * 4);
    int*   blk     = (int*)carve(512 * 4);
    int*   csr_src = (int*)carve((size_t)E * 4);
    float* csr_w   = (float*)carve((size_t)E * 4);
    float* bufA    = (float*)carve((size_t)N * 64 * 4);   // widths <= 64
    float* bufB    = (float*)carve((size_t)N * 128 * 4);  // widths <= 128

    const int NB  = (N + 255) / 256;   // 391 (<=512 required by scan2)
    const int EB  = (E + 255) / 256;
    const int AGB = (N + 3) / 4;       // agg: 4 nodes per 256-thread block

    // --- graph preprocessing: degree, dinv, CSR ---
    zero_kernel<<<NB, 256, 0, stream>>>(cnt, N);
    deg_kernel<<<EB, 256, 0, stream>>>(e_dst, cnt, E);
    dinv_kernel<<<NB, 256, 0, stream>>>(cnt, dinv, N);
    scan1_kernel<<<NB, 256, 0, stream>>>(cnt, row_ptr, blk, N);
    scan2_kernel<<<1, 512, 0, stream>>>(blk, NB);
    scan3_kernel<<<NB, 256, 0, stream>>>(row_ptr, blk, cnt, N, E);
    fill_kernel<<<EB, 256, 0, stream>>>(e_src, e_dst, dinv, cnt, csr_src, csr_w, E);

    // --- L1 (128->16): GEMM first (narrow side), then aggregate+bias+relu ---
    gemm_kernel<128, 16, false><<<(N + 15) / 16, 256, 0, stream>>>(x, W1, nullptr, bufA, N);
    agg_kernel<16, true><<<AGB, 256, 0, stream>>>(bufA, row_ptr, csr_src, csr_w, dinv, b1, bufB, N);

    // --- L2 (16->32): aggregate first, then GEMM+bias+relu ---
    agg_kernel<16, false><<<AGB, 256, 0, stream>>>(bufB, row_ptr, csr_src, csr_w, dinv, nullptr, bufA, N);
    gemm_kernel<16, 32, true><<<(N + 7) / 8, 256, 0, stream>>>(bufA, W2, b2, bufB, N);

    // --- L3 (32->64) ---
    agg_kernel<32, false><<<AGB, 256, 0, stream>>>(bufB, row_ptr, csr_src, csr_w, dinv, nullptr, bufA, N);
    gemm_kernel<32, 64, true><<<(N + 3) / 4, 256, 0, stream>>>(bufA, W3, b3, bufB, N);

    // --- L4 (64->128) ---
    agg_kernel<64, false><<<AGB, 256, 0, stream>>>(bufB, row_ptr, csr_src, csr_w, dinv, nullptr, bufA, N);
    gemm_kernel<64, 128, true><<<(N + 1) / 2, 256, 0, stream>>>(bufA, W4, b4, bufB, N);

    // --- FC head ---
    gemm_kernel<128, 32, true><<<(N + 7) / 8, 256, 0, stream>>>(bufB, Wf1, bf1, bufA, N);
    fc2_tanh_kernel<<<NB, 256, 0, stream>>>(bufA, Wf2, bf2, (float*)d_out, N);
}